// Round 14
// baseline (606.320 us; speedup 1.0000x reference)
//
#include <hip/hip_runtime.h>

#define NV 400000
#define KOFF 27
#define CD 64
#define DD 128
#define HH 128
#define WW 128
#define TABN (2*DD*HH*WW)
#define NCELL 32768
#define EPSV 1e-5f

typedef _Float16 f16;
typedef _Float16 f16x8 __attribute__((ext_vector_type(8)));
typedef float f32x16 __attribute__((ext_vector_type(16)));

// ---- workspace layout (bytes) ----
#define OFF_NBR   0ull
#define OFF_X1    43200000ull
#define OFF_X2    94400000ull
#define OFF_TAB   94400000ull     // table dead before x2 written
#define OFF_HIST  111177216ull    // 32K cells * 4B, inside x2 region (dead after k_hcopy)
#define OFF_FS    111439360ull    // sorted feats, inside x2 region (dead pre-conv2)
#define OFF_W2T   145600000ull
#define OFF_W3T   145821184ull
#define OFF_ZERO  146042368ull
// persistent hist copy lives in nbr slot 13 (freed by orig-packing, see k_nbr2)
#define OFF_HB    (13ull * NV * 4ull)

#define GLDS16(gp, lp) __builtin_amdgcn_global_load_lds( \
    (__attribute__((address_space(1))) void*)(gp), \
    (__attribute__((address_space(3))) void*)(lp), 16, 0, 0)

// ROW-major buckets (b,z,y): cell = (b*128+z)*128+y. Support of an 8-y-cell
// ownership block = 3 CONTIGUOUS rank segments (z-1,z,z+1 x y0-1..y0+8).
__device__ __forceinline__ int cell_of(int4 c) {
    return (c.x * DD + c.y) * HH + c.z;
}

// ---- init: table=-1; hist=0; weights -> f16 chunk-major wTg[k][cin/8][cout][cin&7]
__global__ void k_init(const float* __restrict__ w2, const float* __restrict__ w3,
                       int* __restrict__ tab, f16* __restrict__ w2t,
                       f16* __restrict__ w3t, f16* __restrict__ zrow,
                       int* __restrict__ hist) {
    int t = blockIdx.x * 256 + threadIdx.x;           // grid: 4096*256
    int4* tv = (int4*)tab;
    if (t < TABN / 4) tv[t] = make_int4(-1, -1, -1, -1);
    if (t < NCELL) hist[t] = 0;
    if (t < KOFF * CD * CD) {
        int k = t >> 12, r = t & 4095, c = r >> 6, ci = r & 63;
        int d = (k << 12) + ((ci >> 3) << 9) + (c << 3) + (ci & 7);
        w2t[d] = (f16)w2[(k << 12) + (ci << 6) + c];
        w3t[d] = (f16)w3[(k << 12) + (ci << 6) + c];
    }
    if (t < CD) zrow[t] = (f16)0.f;
}

__global__ void k_hist(const int4* __restrict__ coords, int* __restrict__ hist) {
    int i = blockIdx.x * 256 + threadIdx.x;
    if (i >= NV) return;
    atomicAdd(&hist[cell_of(coords[i])], 1);
}

// exclusive prefix sum over 32768 ints, single workgroup (R11-proven)
__global__ __launch_bounds__(1024) void k_scan(int* __restrict__ hist) {
    __shared__ int part[1024];
    int t = threadIdx.x;
    int base = t * 32;
    int s = 0;
    #pragma unroll
    for (int j = 0; j < 32; j++) s += hist[base + j];
    part[t] = s;
    __syncthreads();
    for (int off = 1; off < 1024; off <<= 1) {
        int v = (t >= off) ? part[t - off] : 0;
        __syncthreads();
        part[t] += v;
        __syncthreads();
    }
    int ex = (t == 0) ? 0 : part[t - 1];
    #pragma unroll
    for (int j = 0; j < 32; j++) {
        int h = hist[base + j];
        hist[base + j] = ex;
        ex += h;
    }
}

// rank assignment. tab[site]=r; nbr[13*NV+r]=orig (TEMP, consumed by k_nbr2);
// feats_s[r]=feats[orig]. Post-rank, hist[c] = END offset of cell c.
__global__ void k_rank(const int4* __restrict__ coords, const float* __restrict__ feats,
                       int* __restrict__ hist, int* __restrict__ tab,
                       int* __restrict__ nbr, float* __restrict__ feats_s) {
    int i = blockIdx.x * 256 + threadIdx.x;
    if (i >= NV) return;
    int4 c = coords[i];
    int r = atomicAdd(&hist[cell_of(c)], 1);
    int flat = ((c.x * DD + c.y) * HH + c.z) * WW + c.w;
    tab[flat] = r;
    nbr[13 * (size_t)NV + r] = i;
    feats_s[r] = feats[i];
}

// rulebook in rank space. ORIG-PACKING: slots 0 and 1 carry (idx+1) in 19 low
// bits plus orig-index bits 0..9 / 10..18 in bits 19+. This frees slot 13 for
// the persistent hist copy (workspace is otherwise exactly full). k=13 skipped.
__global__ void k_nbr2(const int4* __restrict__ coords, const int* __restrict__ tab,
                       int* __restrict__ nbr) {
    int r = blockIdx.x * 256 + threadIdx.x;
    if (r >= NV) return;
    int orig = nbr[13 * (size_t)NV + r];
    int4 c = coords[orig];
    int k = 0;
    #pragma unroll
    for (int dz = -1; dz <= 1; dz++)
    #pragma unroll
    for (int dy = -1; dy <= 1; dy++)
    #pragma unroll
    for (int dx = -1; dx <= 1; dx++) {
        if (k != 13) {
            int z = c.y + dz, y = c.z + dy, x = c.w + dx;
            int idx = -1;
            if (z >= 0 && z < DD && y >= 0 && y < HH && x >= 0 && x < WW)
                idx = tab[((c.x * DD + z) * HH + y) * WW + x];
            int v = idx;
            if (k == 0) v = (idx + 1) | ((orig & 0x3FF) << 19);
            if (k == 1) v = (idx + 1) | (((orig >> 10) & 0x1FF) << 19);
            nbr[(size_t)k * NV + r] = v;
        }
        k++;
    }
}

// copy hist (cell end-offsets) into the freed nbr slot-13 region: survives
// both convs (nbr region is read-only there).
__global__ void k_hcopy(const int* __restrict__ hist, int* __restrict__ hb) {
    int t = blockIdx.x * 256 + threadIdx.x;
    if (t < NCELL) hb[t] = hist[t];
}

// ---- layer 1 (rank space); slots 0/1 unpacked ----
__global__ __launch_bounds__(256) void k_layer1(
        const float* __restrict__ feats_s, const int* __restrict__ nbr,
        const float* __restrict__ w1, const float* __restrict__ b1,
        const float* __restrict__ g1, const float* __restrict__ be1,
        const float* __restrict__ m1, const float* __restrict__ v1,
        f16* __restrict__ x1) {
    int i = blockIdx.x * 256 + threadIdx.x;
    bool act = (i < NV);
    int ii = act ? i : 0;

    float acc[CD];
    #pragma unroll
    for (int c = 0; c < CD; c++) acc[c] = 0.f;

    #pragma unroll
    for (int k = 0; k < KOFF; k++) {
        int idx;
        if (k == 13) idx = ii;
        else {
            idx = act ? nbr[(size_t)k * NV + ii] : -1;
            if (k <= 1 && act) idx = (idx & 0x7FFFF) - 1;
        }
        float fk = (idx >= 0) ? feats_s[idx] : 0.f;
        #pragma unroll
        for (int c = 0; c < CD; c++)
            acc[c] = fmaf(fk, w1[k * CD + c], acc[c]);
    }
    if (!act) return;

    #pragma unroll
    for (int c0 = 0; c0 < CD; c0 += 8) {
        f16x8 o;
        #pragma unroll
        for (int j = 0; j < 8; j++) {
            int c = c0 + j;
            float sc = g1[c] * rsqrtf(v1[c] + EPSV);
            float y = (acc[c] - m1[c] + b1[c]) * sc + be1[c];
            o[j] = (f16)fmaxf(y, 0.f);
        }
        *(f16x8*)(x1 + (size_t)i * CD + c0) = o;
    }
}

// ---- conv v20: HALO-STAGED A. Byte-traffic model (fit to all 13 rounds):
// conv is L2-byte-bound on the A-gather (each row read ~27x = 1.38GB/layer).
// Block = cells (b, z, y0..y0+7), grid 4096. Support = 3 contiguous rank
// segments, staged once (coalesced stream, XOR-swizzled chunks) into a 64KB
// LDS window (cap 511 rows + zero row @511; mean 366, 7-sigma margin).
// Gathers: nbr rank -> segment-relative LDS row (compares), 4x ds_read_b128.
// B-dbuf GLDS + one barrier/body = v11's proven skeleton; 3 vmem ops/body ->
// uniform VMW(1). Tile loop (block-uniform) handles variable voxel counts.
// A L2 traffic 1.38GB -> ~190MB/layer; B 905MB; LDS becomes the busy pipe.
#define MFMA3216(a, b, c) __builtin_amdgcn_mfma_f32_32x32x16_f16(a, b, c, 0, 0, 0)
#define VMW_(n) asm volatile("s_waitcnt vmcnt(" #n ")" ::: "memory")
#define VMW(n) VMW_(n)

#define CONV_BODY(K)                                                            \
  {                                                                             \
    VMW(1);                                                                     \
    __builtin_amdgcn_s_barrier();                                               \
    asm volatile("" ::: "memory");                                              \
    if ((K) + 1 < KOFF) {                                                       \
      _Pragma("unroll")                                                         \
      for (int it = 0; it < 2; it++) {                                          \
        const char* gp = (const char*)wT + ((size_t)((K) + 1) * 8192            \
                          + it * 4096 + tid * 16);                              \
        char* lp = (char*)smem + 65536 + (((K) + 1) & 1) * 8192                 \
                          + it * 4096 + wv * 1024;                              \
        GLDS16(gp, lp);                                                         \
      }                                                                         \
    }                                                                           \
    int iwN = idxC;                                                             \
    if ((K) + 1 < KOFF) {                                                       \
      int rv = nbr[(size_t)((K) + 1) * NV + rAddr];                             \
      if ((K) + 1 == 1) rv = (rv & 0x7FFFF) - 1;                                \
      iwN = rv;                                                                 \
    }                                                                           \
    int lrK;                                                                    \
    if ((K) == 13) lrK = lrSelf;                                                \
    else {                                                                      \
      int v = idxC;                                                             \
      lrK = 511;                                                                \
      lrK = (v >= s1q && v < e1q) ? (base1 + v - s1q) : lrK;                    \
      lrK = (v >= s0q && v < e0q) ? (v - s0q) : lrK;                            \
      lrK = (v >= s2q && v < e2q) ? (base2 + v - s2q) : lrK;                    \
      lrK = lrK > 511 ? 511 : lrK;                                              \
    }                                                                           \
    asm volatile("" ::: "memory");                                              \
    __builtin_amdgcn_s_setprio(1);                                              \
    _Pragma("unroll")                                                           \
    for (int ks = 0; ks < 4; ks++) {                                            \
      const char* bp = (const char*)smem + 65536 + ((K) & 1) * 8192             \
                       + (2 * ks + g) * 1024;                                   \
      f16x8 b0 = *(const f16x8*)(bp + ml * 16);                                 \
      f16x8 b1 = *(const f16x8*)(bp + 512 + ml * 16);                           \
      f16x8 a  = *(const f16x8*)((const char*)smem + lrK * 128                  \
                   + (((2 * ks + g) ^ (lrK & 7)) * 16));                        \
      acc[0] = MFMA3216(a, b0, acc[0]);                                         \
      acc[1] = MFMA3216(a, b1, acc[1]);                                         \
    }                                                                           \
    __builtin_amdgcn_s_setprio(0);                                              \
    idxC = iwN;                                                                 \
  }

template <bool OUTF32>
__global__ __launch_bounds__(256, 2) void k_conv(
        const f16* __restrict__ xin, const f16* __restrict__ wT,
        const int* __restrict__ nbr, const int* __restrict__ hb,
        const float* __restrict__ bb, const float* __restrict__ gg,
        const float* __restrict__ bee, const float* __restrict__ mm,
        const float* __restrict__ vv, void* __restrict__ outp) {
    // 80KB: A support [512 rows x 128B) at [0,65536); B dbuf 2x8KB at
    // [65536,81920) (doubles as epilogue scratch). 2 blocks/CU exactly.
    __shared__ __align__(16) unsigned char smem[81920];

    const int tid = threadIdx.x;
    const int lane = tid & 63;
    const int wv = tid >> 6;
    const int g = lane >> 5;
    const int ml = lane & 31;

    // XCD-chunked swizzle (4096 = 8*512) then decode (b, z, y0)
    int bid = (blockIdx.x & 7) * 512 + (blockIdx.x >> 3);
    const int b  = bid >> 11;
    const int rem = bid & 2047;
    const int z  = rem >> 4;
    const int y0 = (rem & 15) * 8;

    // segment bounds from hist copy (hb[c] = end of cell c)
    const int cb = (b * DD + z) * HH;
    const int yA = (y0 - 1 < 0) ? 0 : y0 - 1;
    const int yZ = (y0 + 8 > 127) ? 127 : y0 + 8;
    int s0q = 0, e0q = 0, s1q, e1q, s2q = 0, e2q = 0;
    if (z > 0) {
        int ca = cb - HH + yA;
        s0q = (ca == 0) ? 0 : hb[ca - 1];
        e0q = hb[cb - HH + yZ];
    }
    {
        int ca = cb + yA;
        s1q = (ca == 0) ? 0 : hb[ca - 1];
        e1q = hb[cb + yZ];
    }
    if (z < DD - 1) {
        int ca = cb + HH + yA;
        s2q = hb[ca - 1];
        e2q = hb[cb + HH + yZ];
    }
    const int n0 = e0q - s0q, n1 = e1q - s1q;
    const int base1 = n0, base2 = n0 + n1;
    int cO = cb + y0;
    const int r0 = (cO == 0) ? 0 : hb[cO - 1];
    const int r1 = hb[cb + y0 + 7];
    const int n = r1 - r0;
    if (n <= 0) return;

    // ---- stage support: 3 coalesced segment streams, swizzled chunks ----
    {
        for (int t = tid; t < n0 * 8; t += 256) {
            int rw = t >> 3, c = t & 7;
            int lr = rw; if (lr > 510) lr = 510;
            f16x8 v = *(const f16x8*)((const char*)xin + (size_t)(s0q + rw) * 128 + c * 16);
            *(f16x8*)((char*)smem + lr * 128 + ((c ^ (lr & 7)) * 16)) = v;
        }
        for (int t = tid; t < n1 * 8; t += 256) {
            int rw = t >> 3, c = t & 7;
            int lr = base1 + rw; if (lr > 510) lr = 510;
            f16x8 v = *(const f16x8*)((const char*)xin + (size_t)(s1q + rw) * 128 + c * 16);
            *(f16x8*)((char*)smem + lr * 128 + ((c ^ (lr & 7)) * 16)) = v;
        }
        int n2 = e2q - s2q;
        for (int t = tid; t < n2 * 8; t += 256) {
            int rw = t >> 3, c = t & 7;
            int lr = base2 + rw; if (lr > 510) lr = 510;
            f16x8 v = *(const f16x8*)((const char*)xin + (size_t)(s2q + rw) * 128 + c * 16);
            *(f16x8*)((char*)smem + lr * 128 + ((c ^ (lr & 7)) * 16)) = v;
        }
        if (tid < 8)
            *(f16x8*)((char*)smem + 511 * 128 + tid * 16) = (f16x8)(f16)0.f;
    }
    __syncthreads();

    const int ntiles = (n + 127) >> 7;
    #pragma unroll 1
    for (int tile = 0; tile < ntiles; tile++) {
        const int tb = r0 + tile * 128;
        int nt = n - tile * 128; if (nt > 128) nt = 128;
        const int rowR = tb + wv * 32 + ml;
        const int rAddr = (rowR < r1) ? rowR : r1 - 1;
        const int lrSelf = base1 + (rAddr - s1q);

        f32x16 acc[2];
        #pragma unroll
        for (int a = 0; a < 2; a++) acc[a] = (f32x16)(0.f);

        // tile prologue: GLDS B(0) into buf 0; idxC = unpacked slot-0 rank
        #pragma unroll
        for (int it = 0; it < 2; it++) {
            const char* gp = (const char*)wT + ((size_t)it * 4096 + tid * 16);
            char* lp = (char*)smem + 65536 + it * 4096 + wv * 1024;
            GLDS16(gp, lp);
        }
        int idxC = (nbr[rAddr] & 0x7FFFF) - 1;
        asm volatile("" ::: "memory");

        CONV_BODY(0)  CONV_BODY(1)  CONV_BODY(2)  CONV_BODY(3)
        CONV_BODY(4)  CONV_BODY(5)  CONV_BODY(6)  CONV_BODY(7)
        CONV_BODY(8)  CONV_BODY(9)  CONV_BODY(10) CONV_BODY(11)
        CONV_BODY(12) CONV_BODY(13) CONV_BODY(14) CONV_BODY(15)
        CONV_BODY(16) CONV_BODY(17) CONV_BODY(18) CONV_BODY(19)
        CONV_BODY(20) CONV_BODY(21) CONV_BODY(22) CONV_BODY(23)
        CONV_BODY(24) CONV_BODY(25) CONV_BODY(26)

        // epilogue: scratch = B region (dead after body 26)
        unsigned char* sS = smem + 65536;
        if (!OUTF32) {
            __syncthreads();
            #pragma unroll
            for (int nt2 = 0; nt2 < 2; nt2++) {
                int cn = nt2 * 32 + ml;
                float sc = gg[cn] * rsqrtf(vv[cn] + EPSV);
                float sh = (bb[cn] - mm[cn]) * sc + bee[cn];
                #pragma unroll
                for (int r = 0; r < 16; r++) {
                    int rowl = wv * 32 + (r & 3) + 8 * (r >> 2) + 4 * g;
                    float y = fmaxf(acc[nt2][r] * sc + sh, 0.f);
                    *(f16*)(sS + rowl * 128 + cn * 2) = (f16)y;
                }
            }
            __syncthreads();
            char* gb = (char*)outp + (size_t)tb * 128;
            int nslot = nt * 8;
            #pragma unroll
            for (int it = 0; it < 4; it++) {
                int s = it * 256 + tid;
                if (s < nslot)
                    *(float4*)(gb + s * 16) = *(const float4*)(sS + s * 16);
            }
            __syncthreads();
        } else {
            #pragma unroll 1
            for (int p = 0; p < 2; p++) {
                __syncthreads();
                if ((wv >> 1) == p) {
                    int lw = wv & 1;
                    #pragma unroll
                    for (int nt2 = 0; nt2 < 2; nt2++) {
                        int cn = nt2 * 32 + ml;
                        float sc = gg[cn] * rsqrtf(vv[cn] + EPSV);
                        float sh = (bb[cn] - mm[cn]) * sc + bee[cn];
                        #pragma unroll
                        for (int r = 0; r < 16; r++) {
                            int rowl = lw * 32 + (r & 3) + 8 * (r >> 2) + 4 * g;
                            float y = fmaxf(acc[nt2][r] * sc + sh, 0.f);
                            *(float*)(sS + rowl * 256 + cn * 4) = y;
                        }
                    }
                }
                __syncthreads();
                #pragma unroll
                for (int it = 0; it < 4; it++) {
                    int s = it * 256 + tid;
                    int gr = tb + p * 64 + (s >> 4);
                    if (gr < r1) {
                        int p0 = nbr[gr];
                        int p1 = nbr[(size_t)NV + gr];
                        int o = ((p0 >> 19) & 0x3FF) | (((p1 >> 19) & 0x1FF) << 10);
                        *(float4*)((char*)outp + (size_t)o * 256 + (s & 15) * 16)
                            = *(const float4*)(sS + s * 16);
                    }
                }
            }
            __syncthreads();
        }
    }
}

extern "C" void kernel_launch(void* const* d_in, const int* in_sizes, int n_in,
                              void* d_out, int out_size, void* d_ws, size_t ws_size,
                              hipStream_t stream) {
    (void)in_sizes; (void)n_in; (void)out_size; (void)ws_size;
    const float* feats = (const float*)d_in[0];
    const int4* coords = (const int4*)d_in[1];
    const float* w1 = (const float*)d_in[2];
    const float* b1 = (const float*)d_in[3];
    const float* g1 = (const float*)d_in[4];
    const float* be1 = (const float*)d_in[5];
    const float* m1 = (const float*)d_in[6];
    const float* v1 = (const float*)d_in[7];
    const float* w2 = (const float*)d_in[8];
    const float* b2 = (const float*)d_in[9];
    const float* g2 = (const float*)d_in[10];
    const float* be2 = (const float*)d_in[11];
    const float* m2 = (const float*)d_in[12];
    const float* v2 = (const float*)d_in[13];
    const float* w3 = (const float*)d_in[14];
    const float* b3 = (const float*)d_in[15];
    const float* g3 = (const float*)d_in[16];
    const float* be3 = (const float*)d_in[17];
    const float* m3 = (const float*)d_in[18];
    const float* v3 = (const float*)d_in[19];

    char* ws = (char*)d_ws;
    int* nbr  = (int*)(ws + OFF_NBR);
    f16* x1   = (f16*)(ws + OFF_X1);
    f16* x2   = (f16*)(ws + OFF_X2);
    int* tab  = (int*)(ws + OFF_TAB);
    int* hist = (int*)(ws + OFF_HIST);
    float* fs = (float*)(ws + OFF_FS);
    f16* w2t  = (f16*)(ws + OFF_W2T);
    f16* w3t  = (f16*)(ws + OFF_W3T);
    f16* zrow = (f16*)(ws + OFF_ZERO);
    int* hb   = (int*)(ws + OFF_HB);

    k_init<<<4096, 256, 0, stream>>>(w2, w3, tab, w2t, w3t, zrow, hist);
    k_hist<<<(NV + 255) / 256, 256, 0, stream>>>(coords, hist);
    k_scan<<<1, 1024, 0, stream>>>(hist);
    k_rank<<<(NV + 255) / 256, 256, 0, stream>>>(coords, feats, hist, tab, nbr, fs);
    k_nbr2<<<(NV + 255) / 256, 256, 0, stream>>>(coords, tab, nbr);
    k_hcopy<<<NCELL / 256, 256, 0, stream>>>(hist, hb);
    k_layer1<<<(NV + 255) / 256, 256, 0, stream>>>(fs, nbr, w1, b1, g1, be1, m1, v1, x1);
    const int convgrid = 4096;   // 2(b) x 128(z) x 16(y-blocks)
    k_conv<false><<<convgrid, 256, 0, stream>>>(x1, w2t, nbr, hb, b2, g2, be2, m2, v2, (void*)x2);
    k_conv<true><<<convgrid, 256, 0, stream>>>(x2, w3t, nbr, hb, b3, g3, be3, m3, v3, d_out);
}

// Round 15
// 537.964 us; speedup vs baseline: 1.1271x; 1.1271x over previous
//
#include <hip/hip_runtime.h>

#define NV 400000
#define KOFF 27
#define CD 64
#define DD 128
#define HH 128
#define WW 128
#define TABN (2*DD*HH*WW)
#define NCELL 32768
#define EPSV 1e-5f

typedef _Float16 f16;
typedef _Float16 f16x8 __attribute__((ext_vector_type(8)));
typedef float f32x16 __attribute__((ext_vector_type(16)));

// ---- workspace layout (bytes) ----
#define OFF_NBR   0ull
#define OFF_X1    43200000ull
#define OFF_X2    94400000ull
#define OFF_TAB   94400000ull     // table dead before x2 written
#define OFF_HIST  111177216ull    // 32K rows * 4B, inside x2 region (dead pre-conv2)
#define OFF_FS    111439360ull    // sorted feats, inside x2 region (dead pre-conv2)
#define OFF_W2T   145600000ull
#define OFF_W3T   145821184ull
#define OFF_ZERO  146042368ull

#define GLDS16(gp, lp) __builtin_amdgcn_global_load_lds( \
    (__attribute__((address_space(1))) void*)(gp), \
    (__attribute__((address_space(3))) void*)(lp), 16, 0, 0)

// ROW-major buckets (b,z,y): locality for tab reads and conv gathers.
__device__ __forceinline__ int cell_of(int4 c) {
    return (c.x * DD + c.y) * HH + c.z;    // (b*128+z)*128+y, < 32768
}

// ---- init: table=-1; hist=0; weights -> f16 chunk-major wTg[k][cin/8][cout][cin&7]
__global__ void k_init(const float* __restrict__ w2, const float* __restrict__ w3,
                       int* __restrict__ tab, f16* __restrict__ w2t,
                       f16* __restrict__ w3t, f16* __restrict__ zrow,
                       int* __restrict__ hist) {
    int t = blockIdx.x * 256 + threadIdx.x;           // grid: 4096*256
    int4* tv = (int4*)tab;
    if (t < TABN / 4) tv[t] = make_int4(-1, -1, -1, -1);
    if (t < NCELL) hist[t] = 0;
    if (t < KOFF * CD * CD) {
        int k = t >> 12, r = t & 4095, c = r >> 6, ci = r & 63;
        int d = (k << 12) + ((ci >> 3) << 9) + (c << 3) + (ci & 7);
        w2t[d] = (f16)w2[(k << 12) + (ci << 6) + c];
        w3t[d] = (f16)w3[(k << 12) + (ci << 6) + c];
    }
    if (t < CD) zrow[t] = (f16)0.f;
}

__global__ void k_hist(const int4* __restrict__ coords, int* __restrict__ hist) {
    int i = blockIdx.x * 256 + threadIdx.x;
    if (i >= NV) return;
    atomicAdd(&hist[cell_of(coords[i])], 1);
}

// exclusive prefix sum over 32768 ints, single workgroup (R11-proven)
__global__ __launch_bounds__(1024) void k_scan(int* __restrict__ hist) {
    __shared__ int part[1024];
    int t = threadIdx.x;
    int base = t * 32;
    int s = 0;
    #pragma unroll
    for (int j = 0; j < 32; j++) s += hist[base + j];
    part[t] = s;
    __syncthreads();
    for (int off = 1; off < 1024; off <<= 1) {
        int v = (t >= off) ? part[t - off] : 0;
        __syncthreads();
        part[t] += v;
        __syncthreads();
    }
    int ex = (t == 0) ? 0 : part[t - 1];
    #pragma unroll
    for (int j = 0; j < 32; j++) {
        int h = hist[base + j];
        hist[base + j] = ex;
        ex += h;
    }
}

// rank r = row-contiguous position. tab[site]=r; nbr[13*NV+r]=orig idx
// (scatter-back permutation); feats_s[r]=feats[orig].
__global__ void k_rank(const int4* __restrict__ coords, const float* __restrict__ feats,
                       int* __restrict__ hist, int* __restrict__ tab,
                       int* __restrict__ nbr, float* __restrict__ feats_s) {
    int i = blockIdx.x * 256 + threadIdx.x;
    if (i >= NV) return;
    int4 c = coords[i];
    int r = atomicAdd(&hist[cell_of(c)], 1);
    int flat = ((c.x * DD + c.y) * HH + c.z) * WW + c.w;
    tab[flat] = r;
    nbr[13 * (size_t)NV + r] = i;
    feats_s[r] = feats[i];
}

// neighbor rulebook in rank space (sorted order -> local tab reads).
// k=13 skipped (slot holds orig index).
__global__ void k_nbr2(const int4* __restrict__ coords, const int* __restrict__ tab,
                       int* __restrict__ nbr) {
    int r = blockIdx.x * 256 + threadIdx.x;
    if (r >= NV) return;
    int orig = nbr[13 * (size_t)NV + r];
    int4 c = coords[orig];
    int k = 0;
    #pragma unroll
    for (int dz = -1; dz <= 1; dz++)
    #pragma unroll
    for (int dy = -1; dy <= 1; dy++)
    #pragma unroll
    for (int dx = -1; dx <= 1; dx++) {
        if (k != 13) {
            int z = c.y + dz, y = c.z + dy, x = c.w + dx;
            int idx = -1;
            if (z >= 0 && z < DD && y >= 0 && y < HH && x >= 0 && x < WW)
                idx = tab[((c.x * DD + z) * HH + y) * WW + x];
            nbr[(size_t)k * NV + r] = idx;
        }
        k++;
    }
}

// ---- layer 1 (rank space): one thread per sorted voxel ----
__global__ __launch_bounds__(256) void k_layer1(
        const float* __restrict__ feats_s, const int* __restrict__ nbr,
        const float* __restrict__ w1, const float* __restrict__ b1,
        const float* __restrict__ g1, const float* __restrict__ be1,
        const float* __restrict__ m1, const float* __restrict__ v1,
        f16* __restrict__ x1) {
    int i = blockIdx.x * 256 + threadIdx.x;   // i = rank
    bool act = (i < NV);
    int ii = act ? i : 0;

    float acc[CD];
    #pragma unroll
    for (int c = 0; c < CD; c++) acc[c] = 0.f;

    #pragma unroll
    for (int k = 0; k < KOFF; k++) {
        int idx = (k == 13) ? ii : (act ? nbr[(size_t)k * NV + ii] : -1);
        float fk = (idx >= 0) ? feats_s[idx] : 0.f;
        #pragma unroll
        for (int c = 0; c < CD; c++)
            acc[c] = fmaf(fk, w1[k * CD + c], acc[c]);
    }
    if (!act) return;

    #pragma unroll
    for (int c0 = 0; c0 < CD; c0 += 8) {
        f16x8 o;
        #pragma unroll
        for (int j = 0; j < 8; j++) {
            int c = c0 + j;
            float sc = g1[c] * rsqrtf(v1[c] + EPSV);
            float y = (acc[c] - m1[c] + b1[c]) * sc + be1[c];
            o[j] = (f16)fmaxf(y, 0.f);
        }
        *(f16x8*)(x1 + (size_t)i * CD + c0) = o;
    }
}

// ---- conv v21: per-lane-source GLDS A-gather (TA line-request fix).
// Pipe budget fit to all 9 variants: TA is the max pipe (~67%) in v11 —
// its 4 A-instr/wave/body re-touch the SAME 32 lines 4x (128 line-cycles
// for 32 lines of data). v21: 8 lanes cooperatively fetch ONE row (1 line)
// DIRECTLY to LDS via global_load_lds with per-lane global source (rule
// #21/s09: source per-lane, dest linear base+lane*16). 4 GLDS/body = 32
// lines (4x cut), no ds_write, no VGPR staging, no lgkm drain (GLDS->ds_read
// ordered by the body-top VMW). A window is WAVE-PRIVATE (4KB x 2 bufs) ->
// zero cross-wave hazards; B keeps v11's proven dbuf+barrier skeleton.
// Bank fix: source chunk pre-swizzled (l&7)^(l>>3); readback XOR (c^(ml&7))
// -> 4-way residual (1.58x, m136). Ranks for the 8-row groups via 4
// ds_bpermute from idxN (lanes 0-31 hold own-voxel ranks); k=13 rows are
// the wave's own contiguous ranks (no bpermute).
// vmem ops/body: 2 B-GLDS + 4 A-GLDS + 1 nbr. VMW(1) bodies 0..25 (drains
// A(K),B(K); leaves nbr in flight), VMW(0) body 26.
// LDS 48KB: A [2][4 waves][4096] at 0; B dbuf [2][8192] at 32768 (doubles
// as epilogue scratch). 3 blocks/CU.
#define MFMA3216(a, b, c) __builtin_amdgcn_mfma_f32_32x32x16_f16(a, b, c, 0, 0, 0)
#define VMW_(n) asm volatile("s_waitcnt vmcnt(" #n ")" ::: "memory")
#define VMW(n) VMW_(n)

#define CONV_BODY(K, WN)                                                        \
  {                                                                             \
    VMW(WN);                                                                    \
    __builtin_amdgcn_s_barrier();                                               \
    asm volatile("" ::: "memory");                                              \
    if ((K) + 1 < KOFF) {                                                       \
      _Pragma("unroll")                                                         \
      for (int it = 0; it < 2; it++) {                                          \
        const char* gp = (const char*)wT + ((size_t)((K) + 1) * 8192            \
                          + it * 4096 + tid * 16);                              \
        char* lp = (char*)smem + 32768 + (((K) + 1) & 1) * 8192                 \
                          + it * 4096 + wv * 1024;                              \
        GLDS16(gp, lp);                                                         \
      }                                                                         \
      _Pragma("unroll")                                                         \
      for (int j = 0; j < 4; j++) {                                             \
        int r8;                                                                 \
        if ((K) + 1 == 13) r8 = rowb + j * 8 + (lane >> 3);                     \
        else r8 = __builtin_amdgcn_ds_bpermute((j * 8 + (lane >> 3)) * 4, idxN);\
        const char* gp = ((r8 >= 0)                                             \
            ? (const char*)xin + (size_t)r8 * 128                               \
            : (const char*)zr) + chnk * 16;                                     \
        char* lp = (char*)smem + (((K) + 1) & 1) * 16384 + wv * 4096            \
                          + j * 1024;                                           \
        GLDS16(gp, lp);                                                         \
      }                                                                         \
    }                                                                           \
    int iwN = idxN;                                                             \
    if ((K) + 2 < KOFF)                                                         \
      iwN = nbr[(size_t)((K) + 2) * NV + row];                                  \
    asm volatile("" ::: "memory");                                              \
    __builtin_amdgcn_s_setprio(1);                                              \
    _Pragma("unroll")                                                           \
    for (int ks = 0; ks < 4; ks++) {                                            \
      const char* bp = (const char*)smem + 32768 + ((K) & 1) * 8192             \
                       + (2 * ks + g) * 1024;                                   \
      f16x8 b0 = *(const f16x8*)(bp + ml * 16);                                 \
      f16x8 b1 = *(const f16x8*)(bp + 512 + ml * 16);                           \
      f16x8 a = *(const f16x8*)((const char*)smem + ((K) & 1) * 16384           \
                   + wv * 4096 + ml * 128 + (((2 * ks + g) ^ (ml & 7)) * 16));  \
      acc[0] = MFMA3216(a, b0, acc[0]);                                         \
      acc[1] = MFMA3216(a, b1, acc[1]);                                         \
    }                                                                           \
    __builtin_amdgcn_s_setprio(0);                                              \
    idxN = iwN;                                                                 \
  }

static_assert(NV % 128 == 0, "grid must tile exactly");

template <bool OUTF32>
__global__ __launch_bounds__(256, 3) void k_conv(
        const f16* __restrict__ xin, const f16* __restrict__ wT,
        const int* __restrict__ nbr, const f16* __restrict__ zr,
        const float* __restrict__ bb, const float* __restrict__ gg,
        const float* __restrict__ bee, const float* __restrict__ mm,
        const float* __restrict__ vv, void* __restrict__ outp) {
    // 48 KB: A [2 bufs][4 waves][4096] at [0,32768); B dbuf [2][8192] at
    // [32768,49152) — B region doubles as the 16KB epilogue scratch.
    __shared__ __align__(16) unsigned char smem[49152];
    unsigned char* sS = smem + 32768;

    const int tid = threadIdx.x;
    const int lane = tid & 63;
    const int wv = tid >> 6;
    const int g = lane >> 5;
    const int ml = lane & 31;
    const int chnk = (lane & 7) ^ (lane >> 3);   // source chunk pre-swizzle
    // bijective XCD-chunked swizzle: grid 3125 = 8*390 + 5
    int bid;
    {
        int x = blockIdx.x & 7, j = blockIdx.x >> 3;
        bid = (x < 5 ? x * 391 : 5 * 391 + (x - 5) * 390) + j;
    }
    const int vbase = bid * 128;
    const int rowb = vbase + wv * 32;         // wave's first voxel (rank)
    const int row = rowb + ml;                // this lane's own voxel

    f32x16 acc[2];
    #pragma unroll
    for (int b = 0; b < 2; b++) acc[b] = (f32x16)(0.f);

    int idxN;

    // prologue: ranks(0) -> bpermute -> A(0) GLDS; B(0) GLDS; idxN = ranks(1)
    {
        int r0v = nbr[row];
        #pragma unroll
        for (int it = 0; it < 2; it++) {
            const char* gp = (const char*)wT + ((size_t)it * 4096 + tid * 16);
            char* lp = (char*)smem + 32768 + it * 4096 + wv * 1024;
            GLDS16(gp, lp);
        }
        #pragma unroll
        for (int j = 0; j < 4; j++) {
            int r8 = __builtin_amdgcn_ds_bpermute((j * 8 + (lane >> 3)) * 4, r0v);
            const char* gp = ((r8 >= 0)
                ? (const char*)xin + (size_t)r8 * 128
                : (const char*)zr) + chnk * 16;
            char* lp = (char*)smem + wv * 4096 + j * 1024;
            GLDS16(gp, lp);
        }
        idxN = nbr[(size_t)NV + row];
    }
    asm volatile("" ::: "memory");

    CONV_BODY(0, 1)
    CONV_BODY(1, 1)
    CONV_BODY(2, 1)
    CONV_BODY(3, 1)
    CONV_BODY(4, 1)
    CONV_BODY(5, 1)
    CONV_BODY(6, 1)
    CONV_BODY(7, 1)
    CONV_BODY(8, 1)
    CONV_BODY(9, 1)
    CONV_BODY(10, 1)
    CONV_BODY(11, 1)
    CONV_BODY(12, 1)
    CONV_BODY(13, 1)
    CONV_BODY(14, 1)
    CONV_BODY(15, 1)
    CONV_BODY(16, 1)
    CONV_BODY(17, 1)
    CONV_BODY(18, 1)
    CONV_BODY(19, 1)
    CONV_BODY(20, 1)
    CONV_BODY(21, 1)
    CONV_BODY(22, 1)
    CONV_BODY(23, 1)
    CONV_BODY(24, 1)
    CONV_BODY(25, 1)
    CONV_BODY(26, 0)

    // epilogue: BN+ReLU -> LDS transpose -> vectorized stores
    if (!OUTF32) {
        __syncthreads();
        #pragma unroll
        for (int nt = 0; nt < 2; nt++) {
            int cn = nt * 32 + ml;
            float sc = gg[cn] * rsqrtf(vv[cn] + EPSV);
            float sh = (bb[cn] - mm[cn]) * sc + bee[cn];
            #pragma unroll
            for (int r = 0; r < 16; r++) {
                int rowl = wv * 32 + (r & 3) + 8 * (r >> 2) + 4 * g;
                float y = fmaxf(acc[nt][r] * sc + sh, 0.f);
                *(f16*)(sS + rowl * 128 + cn * 2) = (f16)y;
            }
        }
        __syncthreads();
        char* gb = (char*)outp + (size_t)vbase * 128;
        #pragma unroll
        for (int it = 0; it < 4; it++) {
            int s = it * 256 + tid;
            *(float4*)(gb + s * 16) = *(const float4*)(sS + s * 16);
        }
    } else {
        // scatter rows back to ORIGINAL voxel order via nbr[13] (orig index)
        #pragma unroll 1
        for (int p = 0; p < 2; p++) {
            __syncthreads();
            if ((wv >> 1) == p) {
                int lw = wv & 1;
                #pragma unroll
                for (int nt = 0; nt < 2; nt++) {
                    int cn = nt * 32 + ml;
                    float sc = gg[cn] * rsqrtf(vv[cn] + EPSV);
                    float sh = (bb[cn] - mm[cn]) * sc + bee[cn];
                    #pragma unroll
                    for (int r = 0; r < 16; r++) {
                        int rowl = lw * 32 + (r & 3) + 8 * (r >> 2) + 4 * g;
                        float y = fmaxf(acc[nt][r] * sc + sh, 0.f);
                        *(float*)(sS + rowl * 256 + cn * 4) = y;
                    }
                }
            }
            __syncthreads();
            #pragma unroll
            for (int it = 0; it < 4; it++) {
                int s = it * 256 + tid;
                int o = nbr[13 * (size_t)NV + vbase + p * 64 + (s >> 4)];
                *(float4*)((char*)outp + (size_t)o * 256 + (s & 15) * 16)
                    = *(const float4*)(sS + s * 16);
            }
        }
    }
}

extern "C" void kernel_launch(void* const* d_in, const int* in_sizes, int n_in,
                              void* d_out, int out_size, void* d_ws, size_t ws_size,
                              hipStream_t stream) {
    (void)in_sizes; (void)n_in; (void)out_size; (void)ws_size;
    const float* feats = (const float*)d_in[0];
    const int4* coords = (const int4*)d_in[1];
    const float* w1 = (const float*)d_in[2];
    const float* b1 = (const float*)d_in[3];
    const float* g1 = (const float*)d_in[4];
    const float* be1 = (const float*)d_in[5];
    const float* m1 = (const float*)d_in[6];
    const float* v1 = (const float*)d_in[7];
    const float* w2 = (const float*)d_in[8];
    const float* b2 = (const float*)d_in[9];
    const float* g2 = (const float*)d_in[10];
    const float* be2 = (const float*)d_in[11];
    const float* m2 = (const float*)d_in[12];
    const float* v2 = (const float*)d_in[13];
    const float* w3 = (const float*)d_in[14];
    const float* b3 = (const float*)d_in[15];
    const float* g3 = (const float*)d_in[16];
    const float* be3 = (const float*)d_in[17];
    const float* m3 = (const float*)d_in[18];
    const float* v3 = (const float*)d_in[19];

    char* ws = (char*)d_ws;
    int* nbr  = (int*)(ws + OFF_NBR);
    f16* x1   = (f16*)(ws + OFF_X1);
    f16* x2   = (f16*)(ws + OFF_X2);
    int* tab  = (int*)(ws + OFF_TAB);
    int* hist = (int*)(ws + OFF_HIST);
    float* fs = (float*)(ws + OFF_FS);
    f16* w2t  = (f16*)(ws + OFF_W2T);
    f16* w3t  = (f16*)(ws + OFF_W3T);
    f16* zrow = (f16*)(ws + OFF_ZERO);

    k_init<<<4096, 256, 0, stream>>>(w2, w3, tab, w2t, w3t, zrow, hist);
    k_hist<<<(NV + 255) / 256, 256, 0, stream>>>(coords, hist);
    k_scan<<<1, 1024, 0, stream>>>(hist);
    k_rank<<<(NV + 255) / 256, 256, 0, stream>>>(coords, feats, hist, tab, nbr, fs);
    k_nbr2<<<(NV + 255) / 256, 256, 0, stream>>>(coords, tab, nbr);
    k_layer1<<<(NV + 255) / 256, 256, 0, stream>>>(fs, nbr, w1, b1, g1, be1, m1, v1, x1);
    const int convgrid = NV / 128;  // 3125, exact
    k_conv<false><<<convgrid, 256, 0, stream>>>(x1, w2t, nbr, zrow, b2, g2, be2, m2, v2, (void*)x2);
    k_conv<true><<<convgrid, 256, 0, stream>>>(x2, w3t, nbr, zrow, b3, g3, be3, m3, v3, d_out);
}